// Round 4
// baseline (289.234 us; speedup 1.0000x reference)
//
#include <hip/hip_runtime.h>
#include <cstdint>

// Problem constants (from reference)
#define BB 32
#define TV 8192
#define KK 64
#define TS 128
#define MARGIN_F 0.1f
#define LAMBDA_F 0.5f

#define TT 256                                 // t-tile per block (R3 geometry)
static constexpr int KSTR = BB * TV;           // pred_intervened stride per k
static constexpr int NTILE = TV / TT;          // 32 tiles per batch

// Workspace: gsa[KK*BB], gsv[KK*BB], gca[KK*BB], len[BB].
// en = (gsv-gsa)/(len-gca).
//
// R7 rationale. R6 post-mortem: butterfly epilogue (288 DS ops/wave) was the
// 88->114us regression; sched_barrier batching never materialized (VGPR 56).
// Counters show nothing busy (VALU 12%, HBM 9%) -> latency-bound. The one
// untested clean lever is WAVES/CU: R3 ran 16 (4 blocks x 4 waves, LDS cap).
// R7: 512-thread blocks (8 waves), same TT=256 / int4 / float4 1KB requests,
// same unroll-4 interleave, same slab epilogue. Each wave: 32 Phase-A rows
// (R5-verified 32-bit half-plane ballot) + 8 Phase-B k's (partials straight
// to slab -> no big register arrays). launch_bounds(512,8) caps VGPR at 64
// -> 4 blocks x 8 waves = 32 waves/CU. Prediction: dur 88 -> 50-65us if wave
// count was the limiter; if occupancy rises but dur flat, the memory path
// itself saturates ~1TB/s for this mix and the lever is traffic, not waves.
__global__ __launch_bounds__(512, 8) void fused_kernel(
    const float* __restrict__ po, const float* __restrict__ pi,
    const int* __restrict__ idx, const int* __restrict__ gt,
    const int* __restrict__ mv,
    float* __restrict__ gsa, float* __restrict__ gsv,
    float* __restrict__ gca, int* __restrict__ len) {
  const int tid = threadIdx.x;
  const int lane = tid & 63;
  const int w = tid >> 6;                      // 0..7

  const int bid = blockIdx.x;
  const int b = bid >> 5;                      // 0..31
  const int tile = ((bid & 31) + b) & 31;      // bijective per b; spreads tiles
  const int t0 = tile * TT;

  __shared__ unsigned ph[8][65];               // 32-bit plane per (row-chunk,k)
  __shared__ unsigned sV[8];                   // valid bits per 32-row chunk
  __shared__ float so[TT];                     // sigmoid(pred_orig) tile
  __shared__ float saL[KK][65];                // per-(k,lane) partials, padded
  __shared__ float svL[KK][65];

  // ---- Phase A ----  wave w owns rows [t0+32w, t0+32w+32)
  const int grow = b * TV + t0 + 32 * w;       // global row base
  const int mvv = (lane < 32) ? mv[grow + lane] : 0;
  const unsigned V32 = (unsigned)__ballot(mvv != 0);
  if (lane == 0) {
    sV[w] = V32;
    if (V32) atomicAdd(&len[b], __popc(V32));
  }
  if (tid < TT) so[tid] = __fdividef(1.f, 1.f + __expf(-po[b * TV + t0 + tid]));

  const int c = idx[lane];                     // lane extracts column for k=lane
  const int csel = c & 3, csh = c >> 2;
  unsigned plane = 0u;
  if (V32 != 0u) {
    const int4* rowp = (const int4*)(gt + (size_t)grow * TS);
#pragma unroll 4
    for (int ch = 0; ch < 16; ++ch) {          // 1KB wave-load covers rows 2ch,2ch+1
      const int4 v = rowp[ch * 64 + lane];
      const unsigned long long b0 = __ballot(v.x > 0);
      const unsigned long long b1 = __ballot(v.y > 0);
      const unsigned long long b2 = __ballot(v.z > 0);
      const unsigned long long b3 = __ballot(v.w > 0);
      const unsigned long long sel =
          (csel == 0) ? b0 : (csel == 1) ? b1 : (csel == 2) ? b2 : b3;
      plane |= (unsigned)((sel >> csh) & 1ull) << (2 * ch);
      plane |= (unsigned)((sel >> (32 + csh)) & 1ull) << (2 * ch + 1);
    }
    plane &= V32;                              // aligned requires valid
  }
  ph[w][lane] = plane;
  __syncthreads();

  // fully-invalid tile: nothing to add
  if ((sV[0] | sV[1] | sV[2] | sV[3] | sV[4] | sV[5] | sV[6] | sV[7]) == 0u)
    return;

  // ---- Phase B ----  lane covers t_local = 4*lane..4*lane+3; wave owns 8 k
  const int g2 = lane >> 3;                    // (4*lane)>>5: 32-row chunk
  const int sh = (lane & 7) * 4;               // (4*lane)&31
  const unsigned vb4 = (sV[g2] >> sh) & 15u;
  const float4 so4 = *(const float4*)&so[lane * 4];
  const float* pib = pi + (size_t)b * TV + t0 + lane * 4;
  const int kbase = w * 8;

#pragma unroll 4
  for (int i = 0; i < 8; ++i) {
    const int k = kbase + i;
    const float4 x = *(const float4*)(pib + (size_t)k * KSTR);
    const unsigned ab4 = (ph[g2][k] >> sh) & 15u;
    const float e0 = fabsf(so4.x - __fdividef(1.f, 1.f + __expf(-x.x)));
    const float e1 = fabsf(so4.y - __fdividef(1.f, 1.f + __expf(-x.y)));
    const float e2 = fabsf(so4.z - __fdividef(1.f, 1.f + __expf(-x.z)));
    const float e3 = fabsf(so4.w - __fdividef(1.f, 1.f + __expf(-x.w)));
    float a = 0.f, vv = 0.f;
    if (ab4 & 1u) a += e0;
    if (vb4 & 1u) vv += e0;
    if (ab4 & 2u) a += e1;
    if (vb4 & 2u) vv += e1;
    if (ab4 & 4u) a += e2;
    if (vb4 & 4u) vv += e2;
    if (ab4 & 8u) a += e3;
    if (vb4 & 8u) vv += e3;
    saL[k][lane] = a;                          // k exclusive to this wave
    svL[k][lane] = vv;
  }
  __syncthreads();

  // ---- Epilogue: block-level slab reduce (R3-proven, no butterflies) ----
  if (tid < KK) {
    const int k = tid;
    float S = 0.f;
    int ca = 0;
#pragma unroll 8
    for (int j = 0; j < 64; ++j) S += saL[k][j];
#pragma unroll
    for (int gg = 0; gg < 8; ++gg) ca += __popc(ph[gg][k]);
    atomicAdd(&gsa[k * BB + b], S);
    if (ca) atomicAdd(&gca[k * BB + b], (float)ca);
  } else if (tid < 2 * KK) {
    const int k = tid - KK;
    float S = 0.f;
#pragma unroll 8
    for (int j = 0; j < 64; ++j) S += svL[k][j];
    atomicAdd(&gsv[k * BB + b], S);
  }
}

// ---------------------------------------------------------------------------
// Finalize: 1 block over the 2048 (k,b) pairs (logic verified in R2/R3).
// ---------------------------------------------------------------------------
__global__ __launch_bounds__(256) void fin_kernel(
    const float* __restrict__ gsa, const float* __restrict__ gsv,
    const float* __restrict__ gca, const int* __restrict__ len,
    float* __restrict__ out) {
  float s = 0.f;
  for (int i = threadIdx.x; i < KK * BB; i += 256) {
    const int b = i & (BB - 1);
    const float ca = gca[i];
    const float cn = (float)len[b] - ca;
    if (ca > 0.f && cn > 0.f) {
      const float sa = gsa[i];
      const float sv = gsv[i];
      const float d = MARGIN_F - (sa / ca - (sv - sa) / cn);
      s += d > 0.f ? d : 0.f;
    }
  }
#pragma unroll
  for (int off = 32; off > 0; off >>= 1) s += __shfl_down(s, off);
  __shared__ float ws4[4];
  if ((threadIdx.x & 63) == 0) ws4[threadIdx.x >> 6] = s;
  __syncthreads();
  if (threadIdx.x == 0) {
    const float S = ws4[0] + ws4[1] + ws4[2] + ws4[3];
    const float ac = S * (1.0f / (float)(KK * BB));
    out[0] = ac;
    out[1] = ac * LAMBDA_F;
  }
}

extern "C" void kernel_launch(void* const* d_in, const int* in_sizes, int n_in,
                              void* d_out, int out_size, void* d_ws, size_t ws_size,
                              hipStream_t stream) {
  const float* pred_orig = (const float*)d_in[0];   // [B,TV] fp32
  const float* pred_int  = (const float*)d_in[1];   // [K,B,TV] fp32
  const int*   idx       = (const int*)d_in[2];     // [K] int32
  const int*   gt        = (const int*)d_in[3];     // [B,TV,TS] int32
  const int*   mv        = (const int*)d_in[4];     // [B,TV] int32
  float* out = (float*)d_out;

  float* gsa = (float*)d_ws;
  float* gsv = gsa + KK * BB;
  float* gca = gsv + KK * BB;
  int*   len = (int*)(gca + KK * BB);

  // zero the 24.7 KB accumulator region (ws re-poisoned to 0xAA each call)
  hipMemsetAsync(d_ws, 0, (size_t)(3 * KK * BB) * sizeof(float) + BB * sizeof(int),
                 stream);
  fused_kernel<<<BB * NTILE, 512, 0, stream>>>(
      pred_orig, pred_int, idx, gt, mv, gsa, gsv, gca, len);
  fin_kernel<<<1, 256, 0, stream>>>(gsa, gsv, gca, len, out);
}

// Round 5
// 259.389 us; speedup vs baseline: 1.1151x; 1.1151x over previous
//
#include <hip/hip_runtime.h>
#include <cstdint>

// Problem constants (from reference)
#define BB 32
#define TV 8192
#define KK 64
#define TS 128
#define MARGIN_F 0.1f
#define LAMBDA_F 0.5f

#define TT 256                                 // t-tile per block
static constexpr int KSTR = BB * TV;           // pred_intervened stride per k
static constexpr int NTILE = TV / TT;          // 32 tiles per batch

// Workspace: gsa[KK*BB], gsv[KK*BB], gca[KK*BB], len[BB].
// en = (gsv-gsa)/(len-gca).
//
// R8: single-variable A/B against the proven 88us R0 kernel. ONLY change:
// tile = ((bid&31)+b)&31 (per-b rotation). In R0, co-resident blocks
// (bid, bid+256, +512, +768) share ONE tile index -> CUs holding tiles
// 16..31 lose ~47% of their blocks to the early-exit (lengths in
// [TV/2,TV]) with no backfill (grid==residency), while tile-0..15 CUs set
// the makespan; the lockstep same-tile quads also stride pi/gt at exact
// 256KB/1MB -> same-channel hotspots. Rotation gives every CU one block
// from each tile quartile. Everything else is byte-identical to R0
// (R5/R6/R7 each bundled this with a second change that regressed on its
// own: 512B requests / butterfly epilogue / 8-wave blocks).
// Prediction: FETCH/WRITE/VGPR/LDS unchanged; dur 88 -> 66-72us if the
// imbalance theory is right; if flat, same-tile clustering was protective
// and the next lever is the Phase-A ballot chain, not scheduling.
__global__ __launch_bounds__(256, 4) void fused_kernel(
    const float* __restrict__ po, const float* __restrict__ pi,
    const int* __restrict__ idx, const int* __restrict__ gt,
    const int* __restrict__ mv,
    float* __restrict__ gsa, float* __restrict__ gsv,
    float* __restrict__ gca, int* __restrict__ len) {
  const int tid = threadIdx.x;
  const int lane = tid & 63;
  const int w = tid >> 6;
  const int bid = blockIdx.x;
  const int b = bid >> 5;                      // log2(NTILE)=5
  const int tile = ((bid & 31) + b) & 31;      // R8: per-b rotation (see above)
  const int t0 = tile * TT;

  __shared__ unsigned long long planes[4][65]; // [group][k], +1 pad
  __shared__ unsigned long long sVg[4];        // valid bits per group
  __shared__ float so[TT];                     // sigmoid(pred_orig) tile
  __shared__ float saL[KK][65];                // per-(k,lane) partials, padded
  __shared__ float svL[KK][65];

  // ---- Phase A ----
  const int r0 = b * TV + t0 + w * 64;         // global row of this wave's group
  const unsigned long long V = __ballot(mv[r0 + lane] != 0);
  if (lane == 0) {
    sVg[w] = V;
    if (V) atomicAdd(&len[b], __popcll(V));
  }
  so[tid] = __fdividef(1.f, 1.f + __expf(-po[b * TV + t0 + tid]));

  const int c = idx[lane];                     // lane extracts column for k=lane
  const int csel = c & 3, csh = c >> 2;
  unsigned long long plane = 0ull;
  if (V != 0ull) {
    const int4* rowp = (const int4*)(gt + (size_t)r0 * TS);
#pragma unroll 4
    for (int ch = 0; ch < 32; ++ch) {
      int4 v = rowp[ch * 64 + lane];           // 1 KB/wave-load = 2 full rows
      unsigned long long b0 = __ballot(v.x > 0);
      unsigned long long b1 = __ballot(v.y > 0);
      unsigned long long b2 = __ballot(v.z > 0);
      unsigned long long b3 = __ballot(v.w > 0);
      unsigned long long sel =
          (csel == 0) ? b0 : (csel == 1) ? b1 : (csel == 2) ? b2 : b3;
      const unsigned long long raw0 = (sel >> csh) & 1ull;          // row 2ch
      const unsigned long long raw1 = (sel >> (32 + csh)) & 1ull;   // row 2ch+1
      plane |= (raw0 << (2 * ch)) | (raw1 << (2 * ch + 1));
    }
    plane &= V;                                // aligned requires valid
  }
  planes[w][lane] = plane;
  __syncthreads();

  // fully-invalid tile (t0 beyond this batch's valid prefix): nothing to add
  if ((sVg[0] | sVg[1] | sVg[2] | sVg[3]) == 0ull) return;

  // ---- Phase B ----  lane handles t_local = lane*4 .. lane*4+3
  const int g = lane >> 4;                     // (lane*4)>>6
  const int sh4 = (lane & 15) * 4;             // (lane*4)&63
  const unsigned vb4 = (unsigned)((sVg[g] >> sh4) & 15ull);
  const float4 so4 = *(const float4*)&so[lane * 4];
  const float* pib = pi + (size_t)b * TV + t0 + lane * 4;

#pragma unroll 4
  for (int kk = 0; kk < 16; ++kk) {
    const int k = w * 16 + kk;                 // this wave's exclusive k
    const float4 xi = *(const float4*)(pib + (size_t)k * KSTR);
    const unsigned ab4 = (unsigned)((planes[g][k] >> sh4) & 15ull);
    float sa = 0.f, sv = 0.f;
    {
      const float e = fabsf(so4.x - __fdividef(1.f, 1.f + __expf(-xi.x)));
      if (ab4 & 1u) sa += e;
      if (vb4 & 1u) sv += e;
    }
    {
      const float e = fabsf(so4.y - __fdividef(1.f, 1.f + __expf(-xi.y)));
      if (ab4 & 2u) sa += e;
      if (vb4 & 2u) sv += e;
    }
    {
      const float e = fabsf(so4.z - __fdividef(1.f, 1.f + __expf(-xi.z)));
      if (ab4 & 4u) sa += e;
      if (vb4 & 4u) sv += e;
    }
    {
      const float e = fabsf(so4.w - __fdividef(1.f, 1.f + __expf(-xi.w)));
      if (ab4 & 8u) sa += e;
      if (vb4 & 8u) sv += e;
    }
    saL[k][lane] = sa;                         // exclusive (k per wave): no race
    svL[k][lane] = sv;
  }
  __syncthreads();

  // ---- Epilogue: block-level reduce, once ----
  if (tid < KK) {
    const int k = tid;
    float S = 0.f;
    int ca = 0;
#pragma unroll 8
    for (int j = 0; j < 64; ++j) S += saL[k][j];
#pragma unroll
    for (int gg = 0; gg < 4; ++gg) ca += __popcll(planes[gg][k]);
    atomicAdd(&gsa[k * BB + b], S);
    if (ca) atomicAdd(&gca[k * BB + b], (float)ca);
  } else if (tid < 2 * KK) {
    const int k = tid - KK;
    float S = 0.f;
#pragma unroll 8
    for (int j = 0; j < 64; ++j) S += svL[k][j];
    atomicAdd(&gsv[k * BB + b], S);
  }
}

// ---------------------------------------------------------------------------
// Finalize: 1 block over the 2048 (k,b) pairs (logic verified in R2/R3).
// ---------------------------------------------------------------------------
__global__ __launch_bounds__(256) void fin_kernel(
    const float* __restrict__ gsa, const float* __restrict__ gsv,
    const float* __restrict__ gca, const int* __restrict__ len,
    float* __restrict__ out) {
  float s = 0.f;
  for (int i = threadIdx.x; i < KK * BB; i += 256) {
    const int b = i & (BB - 1);
    const float ca = gca[i];
    const float cn = (float)len[b] - ca;
    if (ca > 0.f && cn > 0.f) {
      const float sa = gsa[i];
      const float sv = gsv[i];
      const float d = MARGIN_F - (sa / ca - (sv - sa) / cn);
      s += d > 0.f ? d : 0.f;
    }
  }
#pragma unroll
  for (int off = 32; off > 0; off >>= 1) s += __shfl_down(s, off);
  __shared__ float ws4[4];
  if ((threadIdx.x & 63) == 0) ws4[threadIdx.x >> 6] = s;
  __syncthreads();
  if (threadIdx.x == 0) {
    const float S = ws4[0] + ws4[1] + ws4[2] + ws4[3];
    const float ac = S * (1.0f / (float)(KK * BB));
    out[0] = ac;
    out[1] = ac * LAMBDA_F;
  }
}

extern "C" void kernel_launch(void* const* d_in, const int* in_sizes, int n_in,
                              void* d_out, int out_size, void* d_ws, size_t ws_size,
                              hipStream_t stream) {
  const float* pred_orig = (const float*)d_in[0];   // [B,TV] fp32
  const float* pred_int  = (const float*)d_in[1];   // [K,B,TV] fp32
  const int*   idx       = (const int*)d_in[2];     // [K] int32
  const int*   gt        = (const int*)d_in[3];     // [B,TV,TS] int32
  const int*   mv        = (const int*)d_in[4];     // [B,TV] int32
  float* out = (float*)d_out;

  float* gsa = (float*)d_ws;
  float* gsv = gsa + KK * BB;
  float* gca = gsv + KK * BB;
  int*   len = (int*)(gca + KK * BB);

  // zero the 24.7 KB accumulator region (ws re-poisoned to 0xAA each call)
  hipMemsetAsync(d_ws, 0, (size_t)(3 * KK * BB) * sizeof(float) + BB * sizeof(int),
                 stream);
  fused_kernel<<<BB * NTILE, 256, 0, stream>>>(
      pred_orig, pred_int, idx, gt, mv, gsa, gsv, gca, len);
  fin_kernel<<<1, 256, 0, stream>>>(gsa, gsv, gca, len, out);
}